// Round 6
// baseline (237.753 us; speedup 1.0000x reference)
//
#include <hip/hip_runtime.h>
#include <hip/hip_bf16.h>
#include <math.h>

#define NN 2048
#define CHAIN 512
#define KNN 30
#define LRK 10
#define NFIX 40
#define NSLOT 42
#define HPAD 132
#define AGPAD 260

#define OUT_ROT 0
#define OUT_TRANS (NN*9)
#define OUT_BB (NN*9 + NN*3)

#define THREEFRY_PARTITIONABLE 1

__device__ __forceinline__ int xcd_swz(int b){ return ((b & 7) << 8) | (b >> 3); }

// ---------------- threefry2x32, key = (0, 42) ----------------
__device__ __forceinline__ unsigned rotl32(unsigned x, unsigned r){ return (x<<r)|(x>>(32u-r)); }

__device__ __forceinline__ void tf_block(unsigned &x0, unsigned &x1){
  const unsigned k0 = 0u, k1 = 42u, k2 = 0x1BD11BDAu ^ 0u ^ 42u;
  x0 += k0; x1 += k1;
#define TFR(a) x0 += x1; x1 = rotl32(x1,(a)); x1 ^= x0;
  TFR(13) TFR(15) TFR(26) TFR(6)   x0 += k1; x1 += k2 + 1u;
  TFR(17) TFR(29) TFR(16) TFR(24)  x0 += k2; x1 += k0 + 2u;
  TFR(13) TFR(15) TFR(26) TFR(6)   x0 += k0; x1 += k1 + 3u;
  TFR(17) TFR(29) TFR(16) TFR(24)  x0 += k1; x1 += k2 + 4u;
  TFR(13) TFR(15) TFR(26) TFR(6)   x0 += k2; x1 += k0 + 5u;
#undef TFR
}

__device__ __forceinline__ float gumbel_from_bits(unsigned bits){
  float f = __uint_as_float((bits >> 9) | 0x3f800000u) - 1.0f;
  const float tiny = 1.17549435e-38f;
  float u = fmaxf(tiny, f * (1.0f - tiny) + tiny);
  return -logf(-logf(u));
}

__device__ __forceinline__ float gumbel_at(unsigned p){
#if THREEFRY_PARTITIONABLE
  unsigned x0 = 0u, x1 = p;
  tf_block(x0, x1);
  return gumbel_from_bits(x0 ^ x1);
#else
  const unsigned HALF = (NN*(unsigned)NN)/2u;
  unsigned c0, c1; bool lo = p < HALF;
  if(lo){ c0 = p; c1 = p + HALF; } else { c0 = p - HALF; c1 = p; }
  tf_block(c0, c1);
  return gumbel_from_bits(lo ? c0 : c1);
#endif
}

// ---------------- K1: fused prep (4 nodes/block) + topk (1 row/block) ------------
// Blocks [0,2048): topk row i.  Blocks [2048,2560): prep nodes 4*(b-2048)..+3.
// The two roles are data-independent; fusing lets them co-schedule.
__global__ __launch_bounds__(256) void k_pretop(
    const float* __restrict__ rots, const float* __restrict__ trans,
    const float* __restrict__ nf, const float* __restrict__ Wa1,
    const float* __restrict__ Wv, const int* __restrict__ xmask,
    const int* __restrict__ nmask,
    float* __restrict__ P, float* __restrict__ U, float* __restrict__ V,
    int* __restrict__ srcs)
{
  __shared__ __align__(16) char smem[4*4*132*4];
  int bb = blockIdx.x, t = threadIdx.x;

  if(bb < NN){
    // ---------------- topk role ----------------
    unsigned* s_kk = (unsigned*)smem;          // [512]
    unsigned* s_lk = s_kk + CHAIN;             // [512]
    int i = bb;
    int base = (i >> 9) << 9;
    float tx = trans[i*3+0], ty = trans[i*3+1], tz = trans[i*3+2];
    for(int q=t; q<CHAIN; q+=256){
      int j = base + q;
      float dx = __fsub_rn(trans[j*3+0], tx);
      float dy = __fsub_rn(trans[j*3+1], ty);
      float dz = __fsub_rn(trans[j*3+2], tz);
      float d2 = __fadd_rn(__fadd_rn(__fmul_rn(dx,dx),__fmul_rn(dy,dy)),__fmul_rn(dz,dz));
      bool val = (j != i);
      float dm = val ? d2 : 1e30f;
      s_kk[q] = __float_as_uint(dm) ^ 0x80000000u;
      if(val){
        float g = gumbel_at((unsigned)(i*NN + j));
        float sc = __fadd_rn(__fmul_rn(-1.5f, logf(dm)), g);
        unsigned b = __float_as_uint(sc);
        unsigned ord = b ^ ((b & 0x80000000u) ? 0xFFFFFFFFu : 0x80000000u);
        s_lk[q] = ~ord;
      } else {
        s_lk[q] = 0xFFFFFFFFu;
      }
    }
    __syncthreads();
    if(t < 128){
      int w = t >> 6, lane = t & 63;
      unsigned* arr = w ? s_lk : s_kk;
      int K = w ? LRK : KNN;
      int outoff = w ? KNN : 0;
      unsigned long long best = ~0ull;
      for(int q=lane; q<CHAIN; q+=64){
        unsigned long long kk = ((unsigned long long)arr[q]<<32) | (unsigned)q;
        if(kk < best) best = kk;
      }
      for(int k=0;k<K;k++){
        unsigned long long r = best;
        for(int off=32; off; off>>=1){
          unsigned long long o = __shfl_xor(r, off, 64);
          if(o < r) r = o;
        }
        int winq = (int)(unsigned)(r & 0xffffffffull);
        if(lane == 0){
          srcs[i*NFIX + outoff + k] = base + winq;
          arr[winq] = 0xFFFFFFFFu;
        }
        asm volatile("s_waitcnt lgkmcnt(0)" ::: "memory");
        __builtin_amdgcn_wave_barrier();
        if((winq & 63) == lane){
          best = ~0ull;
          for(int q=lane; q<CHAIN; q+=64){
            unsigned long long kk = ((unsigned long long)arr[q]<<32) | (unsigned)q;
            if(kk < best) best = kk;
          }
        }
      }
    }
    return;
  }

  // ---------------- prep role (4 nodes) ----------------
  float (*fr)[4][132] = (float (*)[4][132])smem;
  int n0 = (bb - NN)*4;
  for(int i=t; i<2048; i+=256){
    int nd = i>>9, c = (i>>7)&3, kk = i&127;
    fr[nd][c][kk] = nf[(n0+nd)*512 + c*128 + kk];
  }
  if(t < 4){
    fr[t][0][128] = 0.0f; fr[t][0][129] = 0.0f;
    fr[t][0][130] = (nmask[n0+t] != 0 && xmask[n0+t] == 0) ? 1.0f : 0.0f;
  } else if(t >= 16 && t < 52){
    int q = t - 16; int nd = q/9, r = q%9, a = r/3, i = r%3;
    int n = n0 + nd;
    const float BB[3][3] = {{-0.525f,1.363f,0.0f},{0.f,0.f,0.f},{1.526f,0.f,0.f}};
    float bb_ = rots[n*9+i*3+0]*BB[a][0] + rots[n*9+i*3+1]*BB[a][1]
              + rots[n*9+i*3+2]*BB[a][2] + trans[n*3+i];
    fr[nd][1+i][128+a] = bb_;
  }
  __syncthreads();

  // P (layout [n][u][c], c fastest): weight loaded once per 16 FMA
  float a[4][4];
#pragma unroll
  for(int nd=0;nd<4;nd++)
#pragma unroll
    for(int c=0;c<4;c++) a[nd][c]=0.f;
  for(int j=0;j<128;j+=4){
    float w0=Wv[(j+0)*256+t], w1=Wv[(j+1)*256+t], w2=Wv[(j+2)*256+t], w3=Wv[(j+3)*256+t];
#pragma unroll
    for(int nd=0;nd<4;nd++){
#pragma unroll
      for(int c=0;c<4;c++){
        float4 f4 = *(const float4*)&fr[nd][c][j];
        a[nd][c] += f4.x*w0 + f4.y*w1 + f4.z*w2 + f4.w*w3;
      }
    }
  }
  for(int j=128;j<131;j++){
    float w = Wv[j*256+t];
#pragma unroll
    for(int nd=0;nd<4;nd++)
#pragma unroll
      for(int c=0;c<4;c++) a[nd][c] += fr[nd][c][j]*w;
  }
#pragma unroll
  for(int nd=0;nd<4;nd++){
    float4 v4; v4.x=a[nd][0]; v4.y=a[nd][1]; v4.z=a[nd][2]; v4.w=a[nd][3];
    *(float4*)&P[(n0+nd)*1024 + t*4] = v4;
  }

  // U (t<128) / V (t>=128)
  int k = t & 127;
  int isV = t >> 7;
  const float* Wcol = Wa1 + (isV ? 131*128 : 0);
  float u[4] = {0.f,0.f,0.f,0.f};
  for(int j=0;j<128;j+=4){
    float w0=Wcol[(j+0)*128+k], w1=Wcol[(j+1)*128+k], w2=Wcol[(j+2)*128+k], w3=Wcol[(j+3)*128+k];
#pragma unroll
    for(int nd=0;nd<4;nd++){
      float4 f4 = *(const float4*)&fr[nd][0][j];
      u[nd] += f4.x*w0 + f4.y*w1 + f4.z*w2 + f4.w*w3;
    }
  }
  for(int j=128;j<131;j++){
    float w = Wcol[j*128+k];
#pragma unroll
    for(int nd=0;nd<4;nd++) u[nd] += fr[nd][0][j]*w;
  }
  float* OUT = isV ? V : U;
#pragma unroll
  for(int nd=0;nd<4;nd++) OUT[(n0+nd)*128 + k] = u[nd];
}

// ---------------- K3: edge logits + softmax + agg + @Wo (fused) ----
// LDS: s_H 22.2KB + s_mux 5.4KB (ef -> Wa2t -> agg, disjoint lifetimes) + ~2KB misc
__global__ __launch_bounds__(256, 5) void k_attn(
    const float* __restrict__ trans, const float* __restrict__ Wa1,
    const float* __restrict__ ba1, const float* __restrict__ Wa2,
    const float* __restrict__ Wo,
    const float* __restrict__ U, const float* __restrict__ V,
    const float* __restrict__ P,
    const int* __restrict__ srcs, float* __restrict__ Y)
{
  __shared__ int   s_src[NSLOT];
  __shared__ int   s_val[NSLOT];
  __shared__ float s_dist[NSLOT];
  __shared__ float s_rel[NSLOT];
  __shared__ __align__(16) float s_H[NSLOT*HPAD];   // 22176 B
  __shared__ __align__(16) float s_mux[NSLOT*32];   // 5376 B: ef | wa2t(8*132) | agg(4*260)
  __shared__ float s_att[NSLOT*8];

  int b = blockIdx.x, t = threadIdx.x;
  int d = xcd_swz(b);
  int pos = d & (CHAIN-1);
  int k = t & 127, grp = t >> 7;

  // stage 0: edge meta
  if(t < NSLOT){
    int src;
    if(t < NFIX)      src = srcs[d*NFIX + t];
    else if(t == NFIX) src = (pos > 0)       ? d-1 : d;
    else               src = (pos < CHAIN-1) ? d+1 : d;
    s_src[t] = src;
    float dx = trans[src*3+0]-trans[d*3+0];
    float dy = trans[src*3+1]-trans[d*3+1];
    float dz = trans[src*3+2]-trans[d*3+2];
    float dist = sqrtf(dx*dx + dy*dy + dz*dz + 1e-12f);
    s_dist[t] = dist;
    s_rel[t] = (float)(src - d);
    s_val[t] = (dist > 1e-3f) ? 1 : 0;
  }

  // per-thread Wa1ef column (k fixed per thread -> genuinely register-resident)
  float wreg[32];
#pragma unroll
  for(int f=0; f<32; f++) wreg[f] = Wa1[(262+f)*128 + k];
  float ubias = ba1[k] + V[d*128 + k];
  __syncthreads();

  // stage 1: ef[42][32] -> s_mux
  for(int i=t; i<NSLOT*32; i+=256){
    int e = i >> 5, f = i & 31;
    float v;
    if(f < 16){
      float zz = (s_dist[e] - (float)f * (20.0f/15.0f)) * 0.8f;
      v = expf(-(zz*zz));
    } else {
      int idx = f - 16; int j = idx & 7;
      float fr = expf((float)(2*j) * (float)(-0.5756462732485115));
      float ang = s_rel[e] * fr;
      v = (idx < 8) ? cosf(ang) : sinf(ang);
    }
    s_mux[i] = v;
  }
  __syncthreads();

  // stage 2: H[e][k] = leaky(U[src][k] + V[d][k] + ba1[k] + ef[e].wreg)
  for(int e = grp; e < NSLOT; e += 2){
    float h = ubias + U[s_src[e]*128 + k];
    const float4* efp = (const float4*)(s_mux + e*32);
#pragma unroll
    for(int q=0; q<8; q++){
      float4 ev = efp[q];
      h += ev.x*wreg[4*q+0] + ev.y*wreg[4*q+1] + ev.z*wreg[4*q+2] + ev.w*wreg[4*q+3];
    }
    h = (h >= 0.0f) ? h : 0.01f*h;
    s_H[e*HPAD + k] = h;
  }
  __syncthreads();

  // stage 2.5: Wa2^T -> s_mux (ef dead)
  for(int i=t; i<1024; i+=256){
    int kk = i >> 3, h = i & 7;
    s_mux[h*HPAD + kk] = Wa2[i];
  }
  __syncthreads();

  // stage 3: logits[e][h] = H[e] . Wa2[:,h]
  for(int p = t; p < NSLOT*8; p += 256){
    int e = p >> 3, h = p & 7;
    const float4* Hp = (const float4*)(s_H + e*HPAD);
    const float4* Wp = (const float4*)(s_mux + h*HPAD);
    float acc = 0.f;
#pragma unroll
    for(int q=0; q<32; q++){
      float4 a = Hp[q], w = Wp[q];
      acc += a.x*w.x + a.y*w.y + a.z*w.z + a.w*w.w;
    }
    s_att[p] = s_val[e] ? acc : -1e30f;
  }
  __syncthreads();

  // stage 4: per-head softmax
  if(t < 64){
    int h = t & 7, g = t >> 3;
    float m = -INFINITY;
    for(int e=g; e<NSLOT; e+=8) m = fmaxf(m, s_att[e*8+h]);
    for(int off=8; off<64; off<<=1) m = fmaxf(m, __shfl_xor(m, off, 64));
    m = (m > -5e29f) ? m : 0.0f;
    float z = 0.0f;
    for(int e=g; e<NSLOT; e+=8){
      float p = expf(s_att[e*8+h] - m);
      s_att[e*8+h] = p; z += p;
    }
    for(int off=8; off<64; off<<=1) z += __shfl_xor(z, off, 64);
    float den = z + 1e-9f;
    for(int e=g; e<NSLOT; e+=8) s_att[e*8+h] = s_att[e*8+h] / den;
  }
  __syncthreads();

  // stage 5: agg[u][c] via one dwordx4 per edge (P layout [n][u][c]); -> s_mux as [4][260]
  {
    int h = t >> 5;
    float a0=0.f,a1=0.f,a2=0.f,a3=0.f;
    for(int e=0;e<NSLOT;e++){
      float w = s_att[e*8 + h];
      float4 p4 = *(const float4*)(P + s_src[e]*1024 + t*4);
      a0 += w*p4.x; a1 += w*p4.y; a2 += w*p4.z; a3 += w*p4.w;
    }
    s_mux[0*AGPAD + t] = a0;
    s_mux[1*AGPAD + t] = a1;
    s_mux[2*AGPAD + t] = a2;
    s_mux[3*AGPAD + t] = a3;
  }
  __syncthreads();

  // stage 6: Y[d][c][k] = agg[c] @ Wo, c-pair per thread-half
  {
    int cp = grp*2;
    const float* g0 = s_mux + cp*AGPAD;
    const float* g1 = s_mux + (cp+1)*AGPAD;
    float x0=0.f, x1=0.f;
    for(int u=0; u<256; u+=4){
      float w0=Wo[(u+0)*128+k], w1=Wo[(u+1)*128+k], w2=Wo[(u+2)*128+k], w3=Wo[(u+3)*128+k];
      float4 a0 = *(const float4*)(g0 + u);
      float4 a1 = *(const float4*)(g1 + u);
      x0 += a0.x*w0 + a0.y*w1 + a0.z*w2 + a0.w*w3;
      x1 += a1.x*w0 + a1.y*w1 + a1.z*w2 + a1.w*w3;
    }
    Y[d*512 + cp*128 + k]     = x0;
    Y[d*512 + (cp+1)*128 + k] = x1;
  }
}

// ---------------- K5: per-node MLP chain, 4 nodes/block ------------
__global__ __launch_bounds__(256) void k_node(
    const float* __restrict__ rots, const float* __restrict__ trans,
    const float* __restrict__ Y,
    const float* __restrict__ Wg, const float* __restrict__ Wf1,
    const float* __restrict__ Wf2, const float* __restrict__ Wr1,
    const float* __restrict__ br1, const float* __restrict__ Wr2,
    const float* __restrict__ br2, const float* __restrict__ Wr3,
    const float* __restrict__ br3, const float* __restrict__ Wt,
    const int* __restrict__ nmask, float* __restrict__ out)
{
  __shared__ __align__(16) float s_y[4][4][128];
  __shared__ __align__(16) float s_t1[4][128];
  __shared__ __align__(16) float s_bb0[4][128];
  __shared__ __align__(16) float s_gv[4][3][128];
  __shared__ __align__(16) float s_h1[4][256];
  __shared__ __align__(16) float s_h2[4][128];
  __shared__ float s_sc[4][8];

  int b = blockIdx.x, t = threadIdx.x;
  int half = t >> 7, k = t & 127;
  int nb = half*2;
  int dbase = b*4;
  for(int i=t; i<4*512; i+=256){
    int nd = i>>9, c=(i>>7)&3, kk=i&127;
    s_y[nd][c][kk] = Y[(dbase+nd)*512 + c*128 + kk];
  }
  __syncthreads();

  float g[2]={0.f,0.f}, f1[2]={0.f,0.f};
  for(int j=0;j<128;j+=4){
    float wg0=Wg[(j+0)*128+k], wg1=Wg[(j+1)*128+k], wg2=Wg[(j+2)*128+k], wg3=Wg[(j+3)*128+k];
    float wf0=Wf1[(j+0)*128+k], wf1_=Wf1[(j+1)*128+k], wf2_=Wf1[(j+2)*128+k], wf3=Wf1[(j+3)*128+k];
#pragma unroll
    for(int nn=0;nn<2;nn++){
      float4 yv = *(const float4*)&s_y[nb+nn][0][j];
      g[nn]  += yv.x*wg0 + yv.y*wg1 + yv.z*wg2 + yv.w*wg3;
      f1[nn] += yv.x*wf0 + yv.y*wf1_ + yv.z*wf2_ + yv.w*wf3;
    }
  }
  float gate[2];
#pragma unroll
  for(int nn=0;nn<2;nn++){
    gate[nn] = 1.0f/(1.0f + expf(-g[nn]));
    s_t1[nb+nn][k] = fmaxf(f1[nn], 0.0f);
  }
  __syncthreads();

  float f0[2]={0.f,0.f};
  for(int j=0;j<128;j+=4){
    float w0=Wf2[(j+0)*128+k], w1=Wf2[(j+1)*128+k], w2=Wf2[(j+2)*128+k], w3=Wf2[(j+3)*128+k];
#pragma unroll
    for(int nn=0;nn<2;nn++){
      float4 tv = *(const float4*)&s_t1[nb+nn][j];
      f0[nn] += tv.x*w0 + tv.y*w1 + tv.z*w2 + tv.w*w3;
    }
  }
#pragma unroll
  for(int nn=0;nn<2;nn++){
    int d = dbase + nb + nn;
    float bb0 = s_y[nb+nn][0][k] + f0[nn];
    s_bb0[nb+nn][k] = bb0;
    out[OUT_BB + d*512 + k] = bb0;
#pragma unroll
    for(int c=1;c<4;c++){
      float v = s_y[nb+nn][c][k] * gate[nn];
      s_gv[nb+nn][c-1][k] = v;
      out[OUT_BB + d*512 + c*128 + k] = v;
    }
  }
  __syncthreads();

  float a1[2], a2[2];
  a1[0]=a1[1]=br1[k]; a2[0]=a2[1]=br1[128+k];
  for(int j=0;j<128;j+=4){
    float w10=Wr1[(j+0)*256+k],     w11=Wr1[(j+1)*256+k],     w12=Wr1[(j+2)*256+k],     w13=Wr1[(j+3)*256+k];
    float w20=Wr1[(j+0)*256+128+k], w21=Wr1[(j+1)*256+128+k], w22=Wr1[(j+2)*256+128+k], w23=Wr1[(j+3)*256+128+k];
#pragma unroll
    for(int nn=0;nn<2;nn++){
      float4 bv = *(const float4*)&s_bb0[nb+nn][j];
      a1[nn] += bv.x*w10 + bv.y*w11 + bv.z*w12 + bv.w*w13;
      a2[nn] += bv.x*w20 + bv.y*w21 + bv.z*w22 + bv.w*w23;
    }
  }
#pragma unroll
  for(int nn=0;nn<2;nn++){
    s_h1[nb+nn][k] = fmaxf(a1[nn], 0.0f);
    s_h1[nb+nn][128+k] = fmaxf(a2[nn], 0.0f);
  }
  __syncthreads();

  float a[2]; a[0]=a[1]=br2[k];
  for(int j=0;j<256;j+=4){
    float w0=Wr2[(j+0)*128+k], w1=Wr2[(j+1)*128+k], w2=Wr2[(j+2)*128+k], w3=Wr2[(j+3)*128+k];
#pragma unroll
    for(int nn=0;nn<2;nn++){
      float4 hv = *(const float4*)&s_h1[nb+nn][j];
      a[nn] += hv.x*w0 + hv.y*w1 + hv.z*w2 + hv.w*w3;
    }
  }
#pragma unroll
  for(int nn=0;nn<2;nn++) s_h2[nb+nn][k] = fmaxf(a[nn], 0.0f);
  __syncthreads();

  if(t < 12){
    int nd = t/3, r = t%3;
    float q = br3[r];
    for(int kk=0;kk<128;kk++) q += s_h2[nd][kk] * Wr3[kk*6 + r];
    s_sc[nd][r] = q;
  } else if(t >= 32 && t < 44){
    int q2 = t-32; int nd = q2/3, i = q2%3;
    float s = 0.f;
    for(int kk=0;kk<128;kk++) s += s_gv[nd][i][kk] * Wt[kk];
    s_sc[nd][4+i] = s;
  }
  __syncthreads();

  if(t < 4){
    int d = dbase + t;
    int nz = nmask[d];
    float q1=s_sc[t][0], q2=s_sc[t][1], q3=s_sc[t][2];
    float nrm = sqrtf(1.0f + q1*q1 + q2*q2 + q3*q3);
    float w=1.0f/nrm, x=q1/nrm, y=q2/nrm, z=q3/nrm;
    float Ru[3][3];
    Ru[0][0]=1.f-2.f*(y*y+z*z); Ru[0][1]=2.f*(x*y-w*z);     Ru[0][2]=2.f*(x*z+w*y);
    Ru[1][0]=2.f*(x*y+w*z);     Ru[1][1]=1.f-2.f*(x*x+z*z); Ru[1][2]=2.f*(y*z-w*x);
    Ru[2][0]=2.f*(x*z-w*y);     Ru[2][1]=2.f*(y*z+w*x);     Ru[2][2]=1.f-2.f*(x*x+y*y);
    for(int i=0;i<3;i++){
      for(int j=0;j<3;j++){
        float rv;
        if(nz){
          rv = rots[d*9+i*3+0]*Ru[0][j] + rots[d*9+i*3+1]*Ru[1][j] + rots[d*9+i*3+2]*Ru[2][j];
        } else {
          rv = rots[d*9+i*3+j];
        }
        out[OUT_ROT + d*9 + i*3 + j] = rv;
      }
      float tv = trans[d*3+i];
      out[OUT_TRANS + d*3 + i] = nz ? (tv + s_sc[t][4+i]) : tv;
    }
  }
}

extern "C" void kernel_launch(void* const* d_in, const int* in_sizes, int n_in,
                              void* d_out, int out_size, void* d_ws, size_t ws_size,
                              hipStream_t stream)
{
  (void)in_sizes; (void)n_in; (void)out_size; (void)ws_size;
  const float* rots = (const float*)d_in[0];
  const float* trans = (const float*)d_in[1];
  const float* nf   = (const float*)d_in[2];
  const float* Wa1  = (const float*)d_in[3];
  const float* ba1  = (const float*)d_in[4];
  const float* Wa2  = (const float*)d_in[5];
  const float* Wv   = (const float*)d_in[6];
  const float* Wo   = (const float*)d_in[7];
  const float* Wg   = (const float*)d_in[8];
  const float* Wf1  = (const float*)d_in[9];
  const float* Wf2  = (const float*)d_in[10];
  const float* Wr1  = (const float*)d_in[11];
  const float* br1  = (const float*)d_in[12];
  const float* Wr2  = (const float*)d_in[13];
  const float* br2  = (const float*)d_in[14];
  const float* Wr3  = (const float*)d_in[15];
  const float* br3  = (const float*)d_in[16];
  const float* Wt   = (const float*)d_in[17];
  const int* xmask  = (const int*)d_in[19];
  const int* nmask  = (const int*)d_in[20];

  float* P = (float*)d_ws;                 // NN*1024 f32  (8 MB), layout [n][u][c]
  float* U = P + NN*1024;                  // NN*128       (1 MB)
  float* V = U + NN*128;                   // NN*128       (1 MB)
  int* srcs = (int*)(V + NN*128);          // NN*40 int    (320 KB)
  float* Y  = (float*)(srcs + NN*NFIX);    // NN*512 f32   (4 MB)

  k_pretop<<<NN + NN/4, 256, 0, stream>>>(rots, trans, nf, Wa1, Wv, xmask, nmask,
                                          P, U, V, srcs);
  k_attn<<<NN, 256, 0, stream>>>(trans, Wa1, ba1, Wa2, Wo, U, V, P, srcs, Y);
  k_node<<<NN/4, 256, 0, stream>>>(rots, trans, Y, Wg, Wf1, Wf2,
                                   Wr1, br1, Wr2, br2, Wr3, br3, Wt,
                                   nmask, (float*)d_out);
}

// Round 7
// 141.028 us; speedup vs baseline: 1.6859x; 1.6859x over previous
//
#include <hip/hip_runtime.h>
#include <hip/hip_bf16.h>
#include <math.h>

#define NN 2048
#define CHAIN 512
#define KNN 30
#define LRK 10
#define NFIX 40
#define NSLOT 42
#define HPAD 132
#define AGPAD 260
#define NREL 1023

#define OUT_ROT 0
#define OUT_TRANS (NN*9)
#define OUT_BB (NN*9 + NN*3)

#define THREEFRY_PARTITIONABLE 1

__device__ __forceinline__ int xcd_swz(int b){ return ((b & 7) << 8) | (b >> 3); }

// ---------------- threefry2x32, key = (0, 42) ----------------
__device__ __forceinline__ unsigned rotl32(unsigned x, unsigned r){ return (x<<r)|(x>>(32u-r)); }

__device__ __forceinline__ void tf_block(unsigned &x0, unsigned &x1){
  const unsigned k0 = 0u, k1 = 42u, k2 = 0x1BD11BDAu ^ 0u ^ 42u;
  x0 += k0; x1 += k1;
#define TFR(a) x0 += x1; x1 = rotl32(x1,(a)); x1 ^= x0;
  TFR(13) TFR(15) TFR(26) TFR(6)   x0 += k1; x1 += k2 + 1u;
  TFR(17) TFR(29) TFR(16) TFR(24)  x0 += k2; x1 += k0 + 2u;
  TFR(13) TFR(15) TFR(26) TFR(6)   x0 += k0; x1 += k1 + 3u;
  TFR(17) TFR(29) TFR(16) TFR(24)  x0 += k1; x1 += k2 + 4u;
  TFR(13) TFR(15) TFR(26) TFR(6)   x0 += k2; x1 += k0 + 5u;
#undef TFR
}

__device__ __forceinline__ float gumbel_from_bits(unsigned bits){
  float f = __uint_as_float((bits >> 9) | 0x3f800000u) - 1.0f;
  const float tiny = 1.17549435e-38f;
  float u = fmaxf(tiny, f * (1.0f - tiny) + tiny);
  return -logf(-logf(u));
}

__device__ __forceinline__ float gumbel_at(unsigned p){
#if THREEFRY_PARTITIONABLE
  unsigned x0 = 0u, x1 = p;
  tf_block(x0, x1);
  return gumbel_from_bits(x0 ^ x1);
#else
  const unsigned HALF = (NN*(unsigned)NN)/2u;
  unsigned c0, c1; bool lo = p < HALF;
  if(lo){ c0 = p; c1 = p + HALF; } else { c0 = p - HALF; c1 = p; }
  tf_block(c0, c1);
  return gumbel_from_bits(lo ? c0 : c1);
#endif
}

// ---------------- K1: fused topk / prep / rel-table (block-role split) ------------
// Blocks [0,NN): topk row.  [NN,NN+512): prep 4 nodes.  [NN+512,NN+1024): Trel 2 rows.
__global__ __launch_bounds__(256) void k_pretop(
    const float* __restrict__ rots, const float* __restrict__ trans,
    const float* __restrict__ nf, const float* __restrict__ Wa1,
    const float* __restrict__ Wv, const int* __restrict__ xmask,
    const int* __restrict__ nmask,
    float* __restrict__ P, float* __restrict__ U, float* __restrict__ V,
    int* __restrict__ srcs, float* __restrict__ Trel)
{
  __shared__ __align__(16) char smem[4*4*132*4];
  int bb = blockIdx.x, t = threadIdx.x;

  if(bb >= NN + 512){
    // ---------------- Trel role: T[r][k] = relpos(r-511) @ Wa1[278..293] ----------
    int r = (bb - (NN+512))*2 + (t >> 7);
    int k = t & 127;
    if(r < NREL){
      float rel = (float)(r - 511);
      float acc = 0.f;
#pragma unroll
      for(int j=0;j<8;j++){
        float fr = expf((float)(2*j) * (float)(-0.5756462732485115));
        float ang = rel * fr;
        acc += cosf(ang) * Wa1[(278+j)*128 + k];
        acc += sinf(ang) * Wa1[(286+j)*128 + k];
      }
      Trel[r*128 + k] = acc;
    }
    return;
  }

  if(bb < NN){
    // ---------------- topk role ----------------
    unsigned* s_kk = (unsigned*)smem;          // [512]
    unsigned* s_lk = s_kk + CHAIN;             // [512]
    int i = bb;
    int base = (i >> 9) << 9;
    float tx = trans[i*3+0], ty = trans[i*3+1], tz = trans[i*3+2];
    for(int q=t; q<CHAIN; q+=256){
      int j = base + q;
      float dx = __fsub_rn(trans[j*3+0], tx);
      float dy = __fsub_rn(trans[j*3+1], ty);
      float dz = __fsub_rn(trans[j*3+2], tz);
      float d2 = __fadd_rn(__fadd_rn(__fmul_rn(dx,dx),__fmul_rn(dy,dy)),__fmul_rn(dz,dz));
      bool val = (j != i);
      float dm = val ? d2 : 1e30f;
      s_kk[q] = __float_as_uint(dm) ^ 0x80000000u;
      if(val){
        float g = gumbel_at((unsigned)(i*NN + j));
        float sc = __fadd_rn(__fmul_rn(-1.5f, logf(dm)), g);
        unsigned b = __float_as_uint(sc);
        unsigned ord = b ^ ((b & 0x80000000u) ? 0xFFFFFFFFu : 0x80000000u);
        s_lk[q] = ~ord;
      } else {
        s_lk[q] = 0xFFFFFFFFu;
      }
    }
    __syncthreads();
    if(t < 128){
      int w = t >> 6, lane = t & 63;
      unsigned* arr = w ? s_lk : s_kk;
      int K = w ? LRK : KNN;
      int outoff = w ? KNN : 0;
      unsigned long long best = ~0ull;
      for(int q=lane; q<CHAIN; q+=64){
        unsigned long long kk = ((unsigned long long)arr[q]<<32) | (unsigned)q;
        if(kk < best) best = kk;
      }
      for(int k=0;k<K;k++){
        unsigned long long r = best;
        for(int off=32; off; off>>=1){
          unsigned long long o = __shfl_xor(r, off, 64);
          if(o < r) r = o;
        }
        int winq = (int)(unsigned)(r & 0xffffffffull);
        if(lane == 0){
          srcs[i*NFIX + outoff + k] = base + winq;
          arr[winq] = 0xFFFFFFFFu;
        }
        asm volatile("s_waitcnt lgkmcnt(0)" ::: "memory");
        __builtin_amdgcn_wave_barrier();
        if((winq & 63) == lane){
          best = ~0ull;
          for(int q=lane; q<CHAIN; q+=64){
            unsigned long long kk = ((unsigned long long)arr[q]<<32) | (unsigned)q;
            if(kk < best) best = kk;
          }
        }
      }
    }
    return;
  }

  // ---------------- prep role (4 nodes) ----------------
  float (*fr)[4][132] = (float (*)[4][132])smem;
  int n0 = (bb - NN)*4;
  for(int i=t; i<2048; i+=256){
    int nd = i>>9, c = (i>>7)&3, kk = i&127;
    fr[nd][c][kk] = nf[(n0+nd)*512 + c*128 + kk];
  }
  if(t < 4){
    fr[t][0][128] = 0.0f; fr[t][0][129] = 0.0f;
    fr[t][0][130] = (nmask[n0+t] != 0 && xmask[n0+t] == 0) ? 1.0f : 0.0f;
  } else if(t >= 16 && t < 52){
    int q = t - 16; int nd = q/9, r = q%9, a = r/3, i = r%3;
    int n = n0 + nd;
    const float BB[3][3] = {{-0.525f,1.363f,0.0f},{0.f,0.f,0.f},{1.526f,0.f,0.f}};
    float bb_ = rots[n*9+i*3+0]*BB[a][0] + rots[n*9+i*3+1]*BB[a][1]
              + rots[n*9+i*3+2]*BB[a][2] + trans[n*3+i];
    fr[nd][1+i][128+a] = bb_;
  }
  __syncthreads();

  float a[4][4];
#pragma unroll
  for(int nd=0;nd<4;nd++)
#pragma unroll
    for(int c=0;c<4;c++) a[nd][c]=0.f;
  for(int j=0;j<128;j+=4){
    float w0=Wv[(j+0)*256+t], w1=Wv[(j+1)*256+t], w2=Wv[(j+2)*256+t], w3=Wv[(j+3)*256+t];
#pragma unroll
    for(int nd=0;nd<4;nd++){
#pragma unroll
      for(int c=0;c<4;c++){
        float4 f4 = *(const float4*)&fr[nd][c][j];
        a[nd][c] += f4.x*w0 + f4.y*w1 + f4.z*w2 + f4.w*w3;
      }
    }
  }
  for(int j=128;j<131;j++){
    float w = Wv[j*256+t];
#pragma unroll
    for(int nd=0;nd<4;nd++)
#pragma unroll
      for(int c=0;c<4;c++) a[nd][c] += fr[nd][c][j]*w;
  }
#pragma unroll
  for(int nd=0;nd<4;nd++){
    float4 v4; v4.x=a[nd][0]; v4.y=a[nd][1]; v4.z=a[nd][2]; v4.w=a[nd][3];
    *(float4*)&P[(n0+nd)*1024 + t*4] = v4;   // layout [n][u][c]
  }

  int k = t & 127;
  int isV = t >> 7;
  const float* Wcol = Wa1 + (isV ? 131*128 : 0);
  float u[4] = {0.f,0.f,0.f,0.f};
  for(int j=0;j<128;j+=4){
    float w0=Wcol[(j+0)*128+k], w1=Wcol[(j+1)*128+k], w2=Wcol[(j+2)*128+k], w3=Wcol[(j+3)*128+k];
#pragma unroll
    for(int nd=0;nd<4;nd++){
      float4 f4 = *(const float4*)&fr[nd][0][j];
      u[nd] += f4.x*w0 + f4.y*w1 + f4.z*w2 + f4.w*w3;
    }
  }
  for(int j=128;j<131;j++){
    float w = Wcol[j*128+k];
#pragma unroll
    for(int nd=0;nd<4;nd++) u[nd] += fr[nd][0][j]*w;
  }
  float* OUT = isV ? V : U;
#pragma unroll
  for(int nd=0;nd<4;nd++) OUT[(n0+nd)*128 + k] = u[nd];
}

// ---------------- K3: edge logits + softmax + agg + @Wo (fused) ----
__global__ __launch_bounds__(256) void k_attn(
    const float* __restrict__ trans, const float* __restrict__ Wa1,
    const float* __restrict__ ba1, const float* __restrict__ Wa2,
    const float* __restrict__ Wo,
    const float* __restrict__ U, const float* __restrict__ V,
    const float* __restrict__ P, const float* __restrict__ Trel,
    const int* __restrict__ srcs, float* __restrict__ Y)
{
  __shared__ int   s_src[NSLOT];
  __shared__ int   s_val[NSLOT];
  __shared__ float s_dist[NSLOT];
  __shared__ __align__(16) float s_H[NSLOT*HPAD];   // 22176 B
  __shared__ __align__(16) float s_mux[NSLOT*32];   // 5376 B: rbf(42*16) | wa2t(8*132) | agg(4*260)
  __shared__ float s_att[NSLOT*8];

  int b = blockIdx.x, t = threadIdx.x;
  int d = xcd_swz(b);
  int pos = d & (CHAIN-1);
  int k = t & 127, grp = t >> 7;

  // stage 0: edge meta
  if(t < NSLOT){
    int src;
    if(t < NFIX)      src = srcs[d*NFIX + t];
    else if(t == NFIX) src = (pos > 0)       ? d-1 : d;
    else               src = (pos < CHAIN-1) ? d+1 : d;
    s_src[t] = src;
    float dx = trans[src*3+0]-trans[d*3+0];
    float dy = trans[src*3+1]-trans[d*3+1];
    float dz = trans[src*3+2]-trans[d*3+2];
    float dist = sqrtf(dx*dx + dy*dy + dz*dz + 1e-12f);
    s_dist[t] = dist;
    s_val[t] = (dist > 1e-3f) ? 1 : 0;
  }

  // per-thread rbf weight column (16 floats -> stays in VGPRs)
  float wreg[16];
#pragma unroll
  for(int f=0; f<16; f++) wreg[f] = Wa1[(262+f)*128 + k];
  float ubias = ba1[k] + V[d*128 + k];
  __syncthreads();

  // stage 1: rbf[42][16]
  for(int i=t; i<NSLOT*16; i+=256){
    int e = i >> 4, f = i & 15;
    float zz = (s_dist[e] - (float)f * (20.0f/15.0f)) * 0.8f;
    s_mux[i] = expf(-(zz*zz));
  }
  __syncthreads();

  // stage 2: H[e][k] = leaky(U[src][k] + Trel[src-d+511][k] + ubias + rbf[e].wreg)
  for(int e = grp; e < NSLOT; e += 2){
    int src = s_src[e];
    float h = ubias + U[src*128 + k] + Trel[(src - d + 511)*128 + k];
    const float4* rp = (const float4*)(s_mux + e*16);
#pragma unroll
    for(int q=0; q<4; q++){
      float4 ev = rp[q];
      h += ev.x*wreg[4*q+0] + ev.y*wreg[4*q+1] + ev.z*wreg[4*q+2] + ev.w*wreg[4*q+3];
    }
    h = (h >= 0.0f) ? h : 0.01f*h;
    s_H[e*HPAD + k] = h;
  }
  __syncthreads();

  // stage 2.5: Wa2^T -> s_mux (rbf dead)
  for(int i=t; i<1024; i+=256){
    int kk = i >> 3, h = i & 7;
    s_mux[h*HPAD + kk] = Wa2[i];
  }
  __syncthreads();

  // stage 3: logits[e][h] = H[e] . Wa2[:,h]
  for(int p = t; p < NSLOT*8; p += 256){
    int e = p >> 3, h = p & 7;
    const float4* Hp = (const float4*)(s_H + e*HPAD);
    const float4* Wp = (const float4*)(s_mux + h*HPAD);
    float acc = 0.f;
#pragma unroll
    for(int q=0; q<32; q++){
      float4 a = Hp[q], w = Wp[q];
      acc += a.x*w.x + a.y*w.y + a.z*w.z + a.w*w.w;
    }
    s_att[p] = s_val[e] ? acc : -1e30f;
  }
  __syncthreads();

  // stage 4: per-head softmax
  if(t < 64){
    int h = t & 7, g = t >> 3;
    float m = -INFINITY;
    for(int e=g; e<NSLOT; e+=8) m = fmaxf(m, s_att[e*8+h]);
    for(int off=8; off<64; off<<=1) m = fmaxf(m, __shfl_xor(m, off, 64));
    m = (m > -5e29f) ? m : 0.0f;
    float z = 0.0f;
    for(int e=g; e<NSLOT; e+=8){
      float p = expf(s_att[e*8+h] - m);
      s_att[e*8+h] = p; z += p;
    }
    for(int off=8; off<64; off<<=1) z += __shfl_xor(z, off, 64);
    float den = z + 1e-9f;
    for(int e=g; e<NSLOT; e+=8) s_att[e*8+h] = s_att[e*8+h] / den;
  }
  __syncthreads();

  // stage 5: agg[u][c] via one dwordx4 per edge (P layout [n][u][c])
  {
    int h = t >> 5;
    float a0=0.f,a1=0.f,a2=0.f,a3=0.f;
    for(int e=0;e<NSLOT;e++){
      float w = s_att[e*8 + h];
      float4 p4 = *(const float4*)(P + s_src[e]*1024 + t*4);
      a0 += w*p4.x; a1 += w*p4.y; a2 += w*p4.z; a3 += w*p4.w;
    }
    s_mux[0*AGPAD + t] = a0;
    s_mux[1*AGPAD + t] = a1;
    s_mux[2*AGPAD + t] = a2;
    s_mux[3*AGPAD + t] = a3;
  }
  __syncthreads();

  // stage 6: Y[d][c][k] = agg[c] @ Wo
  {
    int cp = grp*2;
    const float* g0 = s_mux + cp*AGPAD;
    const float* g1 = s_mux + (cp+1)*AGPAD;
    float x0=0.f, x1=0.f;
    for(int u=0; u<256; u+=4){
      float w0=Wo[(u+0)*128+k], w1=Wo[(u+1)*128+k], w2=Wo[(u+2)*128+k], w3=Wo[(u+3)*128+k];
      float4 a0 = *(const float4*)(g0 + u);
      float4 a1 = *(const float4*)(g1 + u);
      x0 += a0.x*w0 + a0.y*w1 + a0.z*w2 + a0.w*w3;
      x1 += a1.x*w0 + a1.y*w1 + a1.z*w2 + a1.w*w3;
    }
    Y[d*512 + cp*128 + k]     = x0;
    Y[d*512 + (cp+1)*128 + k] = x1;
  }
}

// ---------------- K5: per-node MLP chain, 4 nodes/block ------------
__global__ __launch_bounds__(256) void k_node(
    const float* __restrict__ rots, const float* __restrict__ trans,
    const float* __restrict__ Y,
    const float* __restrict__ Wg, const float* __restrict__ Wf1,
    const float* __restrict__ Wf2, const float* __restrict__ Wr1,
    const float* __restrict__ br1, const float* __restrict__ Wr2,
    const float* __restrict__ br2, const float* __restrict__ Wr3,
    const float* __restrict__ br3, const float* __restrict__ Wt,
    const int* __restrict__ nmask, float* __restrict__ out)
{
  __shared__ __align__(16) float s_y[4][4][128];
  __shared__ __align__(16) float s_t1[4][128];
  __shared__ __align__(16) float s_bb0[4][128];
  __shared__ __align__(16) float s_gv[4][3][128];
  __shared__ __align__(16) float s_h1[4][256];
  __shared__ __align__(16) float s_h2[4][128];
  __shared__ float s_sc[4][8];

  int b = blockIdx.x, t = threadIdx.x;
  int half = t >> 7, k = t & 127;
  int nb = half*2;
  int dbase = b*4;
  for(int i=t; i<4*512; i+=256){
    int nd = i>>9, c=(i>>7)&3, kk=i&127;
    s_y[nd][c][kk] = Y[(dbase+nd)*512 + c*128 + kk];
  }
  __syncthreads();

  float g[2]={0.f,0.f}, f1[2]={0.f,0.f};
  for(int j=0;j<128;j+=4){
    float wg0=Wg[(j+0)*128+k], wg1=Wg[(j+1)*128+k], wg2=Wg[(j+2)*128+k], wg3=Wg[(j+3)*128+k];
    float wf0=Wf1[(j+0)*128+k], wf1_=Wf1[(j+1)*128+k], wf2_=Wf1[(j+2)*128+k], wf3=Wf1[(j+3)*128+k];
#pragma unroll
    for(int nn=0;nn<2;nn++){
      float4 yv = *(const float4*)&s_y[nb+nn][0][j];
      g[nn]  += yv.x*wg0 + yv.y*wg1 + yv.z*wg2 + yv.w*wg3;
      f1[nn] += yv.x*wf0 + yv.y*wf1_ + yv.z*wf2_ + yv.w*wf3;
    }
  }
  float gate[2];
#pragma unroll
  for(int nn=0;nn<2;nn++){
    gate[nn] = 1.0f/(1.0f + expf(-g[nn]));
    s_t1[nb+nn][k] = fmaxf(f1[nn], 0.0f);
  }
  __syncthreads();

  float f0[2]={0.f,0.f};
  for(int j=0;j<128;j+=4){
    float w0=Wf2[(j+0)*128+k], w1=Wf2[(j+1)*128+k], w2=Wf2[(j+2)*128+k], w3=Wf2[(j+3)*128+k];
#pragma unroll
    for(int nn=0;nn<2;nn++){
      float4 tv = *(const float4*)&s_t1[nb+nn][j];
      f0[nn] += tv.x*w0 + tv.y*w1 + tv.z*w2 + tv.w*w3;
    }
  }
#pragma unroll
  for(int nn=0;nn<2;nn++){
    int d = dbase + nb + nn;
    float bb0 = s_y[nb+nn][0][k] + f0[nn];
    s_bb0[nb+nn][k] = bb0;
    out[OUT_BB + d*512 + k] = bb0;
#pragma unroll
    for(int c=1;c<4;c++){
      float v = s_y[nb+nn][c][k] * gate[nn];
      s_gv[nb+nn][c-1][k] = v;
      out[OUT_BB + d*512 + c*128 + k] = v;
    }
  }
  __syncthreads();

  float a1[2], a2[2];
  a1[0]=a1[1]=br1[k]; a2[0]=a2[1]=br1[128+k];
  for(int j=0;j<128;j+=4){
    float w10=Wr1[(j+0)*256+k],     w11=Wr1[(j+1)*256+k],     w12=Wr1[(j+2)*256+k],     w13=Wr1[(j+3)*256+k];
    float w20=Wr1[(j+0)*256+128+k], w21=Wr1[(j+1)*256+128+k], w22=Wr1[(j+2)*256+128+k], w23=Wr1[(j+3)*256+128+k];
#pragma unroll
    for(int nn=0;nn<2;nn++){
      float4 bv = *(const float4*)&s_bb0[nb+nn][j];
      a1[nn] += bv.x*w10 + bv.y*w11 + bv.z*w12 + bv.w*w13;
      a2[nn] += bv.x*w20 + bv.y*w21 + bv.z*w22 + bv.w*w23;
    }
  }
#pragma unroll
  for(int nn=0;nn<2;nn++){
    s_h1[nb+nn][k] = fmaxf(a1[nn], 0.0f);
    s_h1[nb+nn][128+k] = fmaxf(a2[nn], 0.0f);
  }
  __syncthreads();

  float a[2]; a[0]=a[1]=br2[k];
  for(int j=0;j<256;j+=4){
    float w0=Wr2[(j+0)*128+k], w1=Wr2[(j+1)*128+k], w2=Wr2[(j+2)*128+k], w3=Wr2[(j+3)*128+k];
#pragma unroll
    for(int nn=0;nn<2;nn++){
      float4 hv = *(const float4*)&s_h1[nb+nn][j];
      a[nn] += hv.x*w0 + hv.y*w1 + hv.z*w2 + hv.w*w3;
    }
  }
#pragma unroll
  for(int nn=0;nn<2;nn++) s_h2[nb+nn][k] = fmaxf(a[nn], 0.0f);
  __syncthreads();

  if(t < 12){
    int nd = t/3, r = t%3;
    float q = br3[r];
    for(int kk=0;kk<128;kk++) q += s_h2[nd][kk] * Wr3[kk*6 + r];
    s_sc[nd][r] = q;
  } else if(t >= 32 && t < 44){
    int q2 = t-32; int nd = q2/3, i = q2%3;
    float s = 0.f;
    for(int kk=0;kk<128;kk++) s += s_gv[nd][i][kk] * Wt[kk];
    s_sc[nd][4+i] = s;
  }
  __syncthreads();

  if(t < 4){
    int d = dbase + t;
    int nz = nmask[d];
    float q1=s_sc[t][0], q2=s_sc[t][1], q3=s_sc[t][2];
    float nrm = sqrtf(1.0f + q1*q1 + q2*q2 + q3*q3);
    float w=1.0f/nrm, x=q1/nrm, y=q2/nrm, z=q3/nrm;
    float Ru[3][3];
    Ru[0][0]=1.f-2.f*(y*y+z*z); Ru[0][1]=2.f*(x*y-w*z);     Ru[0][2]=2.f*(x*z+w*y);
    Ru[1][0]=2.f*(x*y+w*z);     Ru[1][1]=1.f-2.f*(x*x+z*z); Ru[1][2]=2.f*(y*z-w*x);
    Ru[2][0]=2.f*(x*z-w*y);     Ru[2][1]=2.f*(y*z+w*x);     Ru[2][2]=1.f-2.f*(x*x+y*y);
    for(int i=0;i<3;i++){
      for(int j=0;j<3;j++){
        float rv;
        if(nz){
          rv = rots[d*9+i*3+0]*Ru[0][j] + rots[d*9+i*3+1]*Ru[1][j] + rots[d*9+i*3+2]*Ru[2][j];
        } else {
          rv = rots[d*9+i*3+j];
        }
        out[OUT_ROT + d*9 + i*3 + j] = rv;
      }
      float tv = trans[d*3+i];
      out[OUT_TRANS + d*3 + i] = nz ? (tv + s_sc[t][4+i]) : tv;
    }
  }
}

extern "C" void kernel_launch(void* const* d_in, const int* in_sizes, int n_in,
                              void* d_out, int out_size, void* d_ws, size_t ws_size,
                              hipStream_t stream)
{
  (void)in_sizes; (void)n_in; (void)out_size; (void)ws_size;
  const float* rots = (const float*)d_in[0];
  const float* trans = (const float*)d_in[1];
  const float* nf   = (const float*)d_in[2];
  const float* Wa1  = (const float*)d_in[3];
  const float* ba1  = (const float*)d_in[4];
  const float* Wa2  = (const float*)d_in[5];
  const float* Wv   = (const float*)d_in[6];
  const float* Wo   = (const float*)d_in[7];
  const float* Wg   = (const float*)d_in[8];
  const float* Wf1  = (const float*)d_in[9];
  const float* Wf2  = (const float*)d_in[10];
  const float* Wr1  = (const float*)d_in[11];
  const float* br1  = (const float*)d_in[12];
  const float* Wr2  = (const float*)d_in[13];
  const float* br2  = (const float*)d_in[14];
  const float* Wr3  = (const float*)d_in[15];
  const float* br3  = (const float*)d_in[16];
  const float* Wt   = (const float*)d_in[17];
  const int* xmask  = (const int*)d_in[19];
  const int* nmask  = (const int*)d_in[20];

  float* P = (float*)d_ws;                 // NN*1024 f32  (8 MB), layout [n][u][c]
  float* U = P + NN*1024;                  // NN*128       (1 MB)
  float* V = U + NN*128;                   // NN*128       (1 MB)
  int* srcs = (int*)(V + NN*128);          // NN*40 int    (320 KB)
  float* Y  = (float*)(srcs + NN*NFIX);    // NN*512 f32   (4 MB)
  float* Trel = Y + NN*512;                // 1023*128 f32 (0.52 MB)

  k_pretop<<<NN + 512 + 512, 256, 0, stream>>>(rots, trans, nf, Wa1, Wv, xmask, nmask,
                                               P, U, V, srcs, Trel);
  k_attn<<<NN, 256, 0, stream>>>(trans, Wa1, ba1, Wa2, Wo, U, V, P, Trel, srcs, Y);
  k_node<<<NN/4, 256, 0, stream>>>(rots, trans, Y, Wg, Wf1, Wf2,
                                   Wr1, br1, Wr2, br2, Wr3, br3, Wt,
                                   nmask, (float*)d_out);
}